// Round 5
// baseline (552.027 us; speedup 1.0000x reference)
//
#include <hip/hip_runtime.h>
#include <hip/hip_cooperative_groups.h>
#include <stdint.h>

namespace cg = cooperative_groups;

// QuantizedBatchNorm (k=8 fake-quant, training forward), NCHW = [64,256,56,56] f32.
//
// Single cooperative kernel, 1024 blocks (256 ch x 4 n-splits) x 256 threads:
//  phase1: read x -> per-(c,s) partial {sum,min,max} -> grid.sync
//  S1    : every block redundantly: mean quant + ctr quant params (monotone
//          extremes from per-channel min/max)
//  phase2: read x (L3-hot) -> fast fma quant level k (exact __fdiv_rn fallback
//          near floor boundaries) -> exact integer {sum k, sum k^2} -> grid.sync
//  S2    : exact var from integer sums -> inv_den/xn/y quant params -> 256-entry
//          per-channel y-LUT in LDS
//  phase3: read x (L3-hot) -> k -> y = lut[k], nontemporal store
// Math is bit-identical to the round-4 3-kernel version (same partition/trees).
// Fallback to the 3-kernel path if cooperative launch is rejected.

#define C_CH 256
#define P4 784                 // float4 per plane (HW/4)
#define PLANE_STRIDE 200704    // float4 stride between planes at fixed c (256*784)
#define NHW_F 200704.0f
#define NHW_D 200704.0
#define TOLB 1e-3f

typedef float natf4 __attribute__((ext_vector_type(4)));

__device__ __forceinline__ float fq(float x, float sc, float qn, float qx) {
  if (sc == 0.0f) return x;                                   // range==0 passthrough
  float cs = __fsub_rn(fminf(fmaxf(x, qn), qx), qn);
  float f  = floorf(__fadd_rn(__fdiv_rn(cs, sc), 0.5f));
  return __fadd_rn(__fmul_rn(f, sc), qn);
}

__device__ __forceinline__ void qparams(float amax, float& sc, float& qn, float& qx) {
  sc = __fdiv_rn(__fmul_rn(2.0f, amax), 255.0f);
  qn = __fmul_rn(-128.0f, sc);                                // nzp = round(127.5) = 128
  qx = __fmul_rn(127.0f, sc);
}

__device__ __forceinline__ float block_max(float v, float* buf4) {
  #pragma unroll
  for (int m = 1; m <= 32; m <<= 1) v = fmaxf(v, __shfl_xor(v, m, 64));
  if ((threadIdx.x & 63) == 0) buf4[threadIdx.x >> 6] = v;
  __syncthreads();
  float r = fmaxf(fmaxf(buf4[0], buf4[1]), fmaxf(buf4[2], buf4[3]));
  __syncthreads();
  return r;
}

// Fast quant level: q ~= (x - m - n1)/s1 via fma; exact __fdiv_rn ref-sequence
// fallback when within TOLB of a floor boundary (|fast-true| <= ~1e-4 << TOLB).
__device__ __forceinline__ uint32_t qlevel(float xv, float r2, float c2,
    float m, float s1, float n1, float x1) {
  float q = fmaf(xv, r2, c2);
  q = fminf(fmaxf(q, 0.0f), 255.0f);
  const float qh = __fadd_rn(q, 0.5f);
  float fl = floorf(qh);
  const float d = __fsub_rn(qh, fl);
  if (__builtin_expect(fminf(d, __fsub_rn(1.0f, d)) < TOLB, 0)) {
    const float tt = __fsub_rn(xv, m);
    const float cs = __fsub_rn(fminf(fmaxf(tt, n1), x1), n1);
    fl = floorf(__fadd_rn(__fdiv_rn(cs, s1), 0.5f));
  }
  return (uint32_t)fl;                                        // in [0,255]
}

// Redundant S1 (thread t <-> channel t; identical in every block).
struct S1Out { float meanc, tmax, tmin, s1, n1, x1; };

__device__ __forceinline__ void s1_compute(const float* __restrict__ psum,
    const float* __restrict__ pmin, const float* __restrict__ pmax,
    const float* __restrict__ run_mean, float* buf4, S1Out& o) {
  const int t = threadIdx.x;
  float sum = __fadd_rn(__fadd_rn(__fadd_rn(psum[4*t], psum[4*t+1]), psum[4*t+2]), psum[4*t+3]);
  float mn = fminf(fminf(pmin[4*t], pmin[4*t+1]), fminf(pmin[4*t+2], pmin[4*t+3]));
  float mx = fmaxf(fmaxf(pmax[4*t], pmax[4*t+1]), fmaxf(pmax[4*t+2], pmax[4*t+3]));
  const float new_mean = __fdiv_rn(sum, NHW_F);
  const float mp = __fadd_rn(__fmul_rn(0.875f, run_mean[t]), __fmul_rn(0.125f, new_mean));
  const float am = block_max(fabsf(mp), buf4);
  float scm, qnm, qxm; qparams(am, scm, qnm, qxm);
  o.meanc = fq(mp, scm, qnm, qxm);
  o.tmax = __fsub_rn(mx, o.meanc);   // (x - mean_c) monotone in x: extremes attained
  o.tmin = __fsub_rn(mn, o.meanc);
  const float a1 = block_max(fmaxf(fabsf(o.tmax), fabsf(o.tmin)), buf4);
  qparams(a1, o.s1, o.n1, o.x1);
}

// S2 body (thread t <-> channel t): exact var from integer sums -> LUT params.
// Writes global quant params s3..x4q and (via bc/lut) this block's channel values.
__device__ __forceinline__ void s2_and_lut(const S1Out& o,
    const uint32_t* __restrict__ pk, const uint32_t* __restrict__ pk2,
    const float* __restrict__ run_var, const float* __restrict__ weight,
    const float* __restrict__ bias, float* buf4, float* bc, float* lut, int c) {
  const int t = threadIdx.x;
  // sum(ctr^2) = s1^2 * sum((k-128)^2) = s1^2 * (sum k^2 - 256 sum k + 16384*N)
  const unsigned long long ssq = (unsigned long long)pk2[4*t] + pk2[4*t+1]
                               + pk2[4*t+2] + pk2[4*t+3];
  const unsigned int skc = pk[4*t] + pk[4*t+1] + pk[4*t+2] + pk[4*t+3];
  const double s1d = (double)o.s1;
  const double sum_ctr2 = s1d * s1d *
      ((double)ssq - 256.0 * (double)skc + 16384.0 * NHW_D);
  const float new_var = (float)(sum_ctr2 / NHW_D);
  const float vp = __fadd_rn(__fmul_rn(0.875f, run_var[t]), __fmul_rn(0.125f, new_var));
  const float av = block_max(fabsf(vp), buf4);
  float scv, qnv, qxv; qparams(av, scv, qnv, qxv);
  const float varc = fq(vp, scv, qnv, qxv);
  const float dp = __fsqrt_rn(__fadd_rn(varc, 1e-5f));
  const float ad = block_max(fabsf(dp), buf4);
  float scd, qnd, qxd; qparams(ad, scd, qnd, qxd);
  const float idc = fq(dp, scd, qnd, qxd);
  const float ctrmax = fq(o.tmax, o.s1, o.n1, o.x1);
  const float ctrmin = fq(o.tmin, o.s1, o.n1, o.x1);
  const float xpmax = __fdiv_rn(ctrmax, idc);
  const float xpmin = __fdiv_rn(ctrmin, idc);
  const float a3 = block_max(fmaxf(fabsf(xpmax), fabsf(xpmin)), buf4);
  float s3, n3, x3; qparams(a3, s3, n3, x3);
  const float xnmax = fq(xpmax, s3, n3, x3);
  const float xnmin = fq(xpmin, s3, n3, x3);
  const float wv = weight[t];
  const float aw = block_max(fabsf(wv), buf4);
  float scw, qnw, qxw; qparams(aw, scw, qnw, qxw);
  const float qw = fq(wv, scw, qnw, qxw);
  const float bv = bias[t];
  const float ab = block_max(fabsf(bv), buf4);
  float scb, qnb, qxb; qparams(ab, scb, qnb, qxb);
  const float qb = fq(bv, scb, qnb, qxb);                     // bias==0 -> passthrough
  const float e1 = __fadd_rn(__fmul_rn(qw, xnmax), qb);
  const float e2 = __fadd_rn(__fmul_rn(qw, xnmin), qb);
  const float a4 = block_max(fmaxf(fabsf(e1), fabsf(e2)), buf4);
  float s4, n4, x4q; qparams(a4, s4, n4, x4q);
  if (t == c) { bc[0] = idc; bc[1] = qw; bc[2] = qb; }
  __syncthreads();
  const float idc_c = bc[0], qw_c = bc[1], qb_c = bc[2];
  // y-LUT for this block's channel: exact ref chain per level t
  const float ctr_t = __fadd_rn(__fmul_rn((float)t, o.s1), o.n1);
  const float xn_t = fq(__fdiv_rn(ctr_t, idc_c), s3, n3, x3);
  lut[t] = fq(__fadd_rn(__fmul_rn(qw_c, xn_t), qb_c), s4, n4, x4q);
  __syncthreads();
}

// ==================== fused cooperative kernel ====================
__global__ __launch_bounds__(256, 4) void k_fused(
    const float4* __restrict__ x4,
    const float* __restrict__ weight, const float* __restrict__ bias,
    const float* __restrict__ run_mean, const float* __restrict__ run_var,
    natf4* __restrict__ y4,
    float* __restrict__ psum, float* __restrict__ pmin, float* __restrict__ pmax,
    uint32_t* __restrict__ pk, uint32_t* __restrict__ pk2) {
  cg::grid_group gg = cg::this_grid();
  __shared__ float buf4[4];
  __shared__ float bc[4];
  __shared__ float lut[256];
  __shared__ float redf[12];
  __shared__ uint32_t redu[8];
  const int c = blockIdx.x, s = blockIdx.y, t = threadIdx.x;
  const int B0 = (s * 16 * C_CH + c) * P4;
  const int w_ = t >> 6;

  // ---------- phase 1: partial {sum, min, max} ----------
  {
    float sum = 0.0f, mn = INFINITY, mx = -INFINITY;
    #pragma unroll 1
    for (int g = 0; g < 7; ++g) {
      float4 v[7];
      #pragma unroll
      for (int j = 0; j < 7; ++j) {
        const int u = t + 256 * (7 * g + j);
        v[j] = x4[B0 + (u / P4) * PLANE_STRIDE + (u % P4)];
      }
      #pragma unroll
      for (int j = 0; j < 7; ++j) {
        const float4 w = v[j];
        sum = __fadd_rn(sum, __fadd_rn(__fadd_rn(w.x, w.y), __fadd_rn(w.z, w.w)));
        mn = fminf(mn, fminf(fminf(w.x, w.y), fminf(w.z, w.w)));
        mx = fmaxf(mx, fmaxf(fmaxf(w.x, w.y), fmaxf(w.z, w.w)));
      }
    }
    #pragma unroll
    for (int m = 1; m <= 32; m <<= 1) {
      sum = __fadd_rn(sum, __shfl_xor(sum, m, 64));
      mn = fminf(mn, __shfl_xor(mn, m, 64));
      mx = fmaxf(mx, __shfl_xor(mx, m, 64));
    }
    if ((t & 63) == 0) { redf[w_] = sum; redf[4 + w_] = mn; redf[8 + w_] = mx; }
    __syncthreads();
    if (t == 0) {
      const int idx = c * 4 + s;
      psum[idx] = __fadd_rn(__fadd_rn(__fadd_rn(redf[0], redf[1]), redf[2]), redf[3]);
      pmin[idx] = fminf(fminf(redf[4], redf[5]), fminf(redf[6], redf[7]));
      pmax[idx] = fmaxf(fmaxf(redf[8], redf[9]), fmaxf(redf[10], redf[11]));
    }
  }
  __threadfence();
  gg.sync();

  // ---------- S1 (redundant per block) ----------
  S1Out o; s1_compute(psum, pmin, pmax, run_mean, buf4, o);
  if (t == c) bc[3] = o.meanc;
  __syncthreads();
  const float m_c = bc[3];
  const double rd = 1.0 / (double)o.s1;
  const float r2 = (float)rd;
  const float c2 = (float)((-(double)m_c - (double)o.n1) * rd);

  // ---------- phase 2: exact integer {sum k, sum k^2} ----------
  {
    int sk = 0, sk2 = 0;   // per-thread exact: sk<=5e4, sk2<=1.27e7
    #pragma unroll 1
    for (int g = 0; g < 7; ++g) {
      float4 v[7];
      #pragma unroll
      for (int j = 0; j < 7; ++j) {
        const int u = t + 256 * (7 * g + j);
        v[j] = x4[B0 + (u / P4) * PLANE_STRIDE + (u % P4)];
      }
      #pragma unroll
      for (int j = 0; j < 7; ++j) {
        const float4 w = v[j];
        const float vv[4] = {w.x, w.y, w.z, w.w};
        #pragma unroll
        for (int e = 0; e < 4; ++e) {
          const uint32_t k = qlevel(vv[e], r2, c2, m_c, o.s1, o.n1, o.x1);
          sk += (int)k; sk2 += (int)(k * k);
        }
      }
    }
    #pragma unroll
    for (int m = 1; m <= 32; m <<= 1) {   // wave sums: sk2 <= 8.2e8 fits int
      sk += __shfl_xor(sk, m, 64);
      sk2 += __shfl_xor(sk2, m, 64);
    }
    if ((t & 63) == 0) { redu[w_] = (uint32_t)sk; redu[4 + w_] = (uint32_t)sk2; }
    __syncthreads();
    if (t == 0) {
      const int idx = c * 4 + s;
      pk[idx]  = redu[0] + redu[1] + redu[2] + redu[3];        // <=1.3e7
      pk2[idx] = redu[4] + redu[5] + redu[6] + redu[7];        // <=3.27e9, fits u32
    }
  }
  __threadfence();
  gg.sync();

  // ---------- S2 + per-channel y-LUT ----------
  s2_and_lut(o, pk, pk2, run_var, weight, bias, buf4, bc, lut, c);

  // ---------- phase 3: y = lut[k], nontemporal store ----------
  #pragma unroll 1
  for (int g = 0; g < 7; ++g) {
    float4 v[7]; int idx[7];
    #pragma unroll
    for (int j = 0; j < 7; ++j) {
      const int u = t + 256 * (7 * g + j);
      idx[j] = B0 + (u / P4) * PLANE_STRIDE + (u % P4);
      v[j] = x4[idx[j]];
    }
    #pragma unroll
    for (int j = 0; j < 7; ++j) {
      const float4 w = v[j];
      natf4 out;
      out.x = lut[qlevel(w.x, r2, c2, m_c, o.s1, o.n1, o.x1)];
      out.y = lut[qlevel(w.y, r2, c2, m_c, o.s1, o.n1, o.x1)];
      out.z = lut[qlevel(w.z, r2, c2, m_c, o.s1, o.n1, o.x1)];
      out.w = lut[qlevel(w.w, r2, c2, m_c, o.s1, o.n1, o.x1)];
      __builtin_nontemporal_store(out, &y4[idx[j]]);          // don't evict x from L3
    }
  }
}

// ==================== fallback 3-kernel path (round-4, passing) ====================
__global__ __launch_bounds__(256) void k_p1(const float4* __restrict__ x4,
    float* __restrict__ psum, float* __restrict__ pmin, float* __restrict__ pmax) {
  const int c = blockIdx.x, s = blockIdx.y, t = threadIdx.x;
  const int B0 = (s * 16 * C_CH + c) * P4;
  float sum = 0.0f, mn = INFINITY, mx = -INFINITY;
  #pragma unroll 1
  for (int g = 0; g < 7; ++g) {
    float4 v[7];
    #pragma unroll
    for (int j = 0; j < 7; ++j) {
      const int u = t + 256 * (7 * g + j);
      v[j] = x4[B0 + (u / P4) * PLANE_STRIDE + (u % P4)];
    }
    #pragma unroll
    for (int j = 0; j < 7; ++j) {
      const float4 w = v[j];
      sum = __fadd_rn(sum, __fadd_rn(__fadd_rn(w.x, w.y), __fadd_rn(w.z, w.w)));
      mn = fminf(mn, fminf(fminf(w.x, w.y), fminf(w.z, w.w)));
      mx = fmaxf(mx, fmaxf(fmaxf(w.x, w.y), fmaxf(w.z, w.w)));
    }
  }
  #pragma unroll
  for (int m = 1; m <= 32; m <<= 1) {
    sum = __fadd_rn(sum, __shfl_xor(sum, m, 64));
    mn = fminf(mn, __shfl_xor(mn, m, 64));
    mx = fmaxf(mx, __shfl_xor(mx, m, 64));
  }
  __shared__ float red[12];
  const int w_ = t >> 6;
  if ((t & 63) == 0) { red[w_] = sum; red[4 + w_] = mn; red[8 + w_] = mx; }
  __syncthreads();
  if (t == 0) {
    const int idx = c * 4 + s;
    psum[idx] = __fadd_rn(__fadd_rn(__fadd_rn(red[0], red[1]), red[2]), red[3]);
    pmin[idx] = fminf(fminf(red[4], red[5]), fminf(red[6], red[7]));
    pmax[idx] = fmaxf(fmaxf(red[8], red[9]), fmaxf(red[10], red[11]));
  }
}

__global__ __launch_bounds__(256) void k_p2(const float4* __restrict__ x4,
    const float* __restrict__ psum, const float* __restrict__ pmin,
    const float* __restrict__ pmax, const float* __restrict__ run_mean,
    uint32_t* __restrict__ pk, uint32_t* __restrict__ pk2) {
  __shared__ float buf4[4];
  __shared__ float bc[1];
  const int c = blockIdx.x, s = blockIdx.y, t = threadIdx.x;
  S1Out o; s1_compute(psum, pmin, pmax, run_mean, buf4, o);
  if (t == c) bc[0] = o.meanc;
  __syncthreads();
  const float m_c = bc[0];
  const double rd = 1.0 / (double)o.s1;
  const float r2 = (float)rd;
  const float c2 = (float)((-(double)m_c - (double)o.n1) * rd);
  const int B0 = (s * 16 * C_CH + c) * P4;
  int sk = 0, sk2 = 0;
  #pragma unroll 1
  for (int g = 0; g < 7; ++g) {
    float4 v[7];
    #pragma unroll
    for (int j = 0; j < 7; ++j) {
      const int u = t + 256 * (7 * g + j);
      v[j] = x4[B0 + (u / P4) * PLANE_STRIDE + (u % P4)];
    }
    #pragma unroll
    for (int j = 0; j < 7; ++j) {
      const float4 w = v[j];
      const float vv[4] = {w.x, w.y, w.z, w.w};
      #pragma unroll
      for (int e = 0; e < 4; ++e) {
        const uint32_t k = qlevel(vv[e], r2, c2, m_c, o.s1, o.n1, o.x1);
        sk += (int)k; sk2 += (int)(k * k);
      }
    }
  }
  #pragma unroll
  for (int m = 1; m <= 32; m <<= 1) {
    sk += __shfl_xor(sk, m, 64);
    sk2 += __shfl_xor(sk2, m, 64);
  }
  __shared__ uint32_t ired[8];
  const int w_ = t >> 6;
  if ((t & 63) == 0) { ired[w_] = (uint32_t)sk; ired[4 + w_] = (uint32_t)sk2; }
  __syncthreads();
  if (t == 0) {
    const int idx = c * 4 + s;
    pk[idx]  = ired[0] + ired[1] + ired[2] + ired[3];
    pk2[idx] = ired[4] + ired[5] + ired[6] + ired[7];
  }
}

__global__ __launch_bounds__(256) void k_p3(const float4* __restrict__ x4,
    const float* __restrict__ psum, const float* __restrict__ pmin,
    const float* __restrict__ pmax, const uint32_t* __restrict__ pk,
    const uint32_t* __restrict__ pk2,
    const float* __restrict__ run_mean, const float* __restrict__ run_var,
    const float* __restrict__ weight, const float* __restrict__ bias,
    natf4* __restrict__ y4) {
  __shared__ float buf4[4];
  __shared__ float bc[4];
  __shared__ float lut[256];
  const int c = blockIdx.x, s = blockIdx.y, t = threadIdx.x;
  S1Out o; s1_compute(psum, pmin, pmax, run_mean, buf4, o);
  if (t == c) bc[3] = o.meanc;
  __syncthreads();
  const float m_c = bc[3];
  s2_and_lut(o, pk, pk2, run_var, weight, bias, buf4, bc, lut, c);
  const double rd = 1.0 / (double)o.s1;
  const float r2 = (float)rd;
  const float c2 = (float)((-(double)m_c - (double)o.n1) * rd);
  const int B0 = (s * 16 * C_CH + c) * P4;
  #pragma unroll 1
  for (int g = 0; g < 7; ++g) {
    float4 v[7]; int idx[7];
    #pragma unroll
    for (int j = 0; j < 7; ++j) {
      const int u = t + 256 * (7 * g + j);
      idx[j] = B0 + (u / P4) * PLANE_STRIDE + (u % P4);
      v[j] = x4[idx[j]];
    }
    #pragma unroll
    for (int j = 0; j < 7; ++j) {
      const float4 w = v[j];
      natf4 out;
      out.x = lut[qlevel(w.x, r2, c2, m_c, o.s1, o.n1, o.x1)];
      out.y = lut[qlevel(w.y, r2, c2, m_c, o.s1, o.n1, o.x1)];
      out.z = lut[qlevel(w.z, r2, c2, m_c, o.s1, o.n1, o.x1)];
      out.w = lut[qlevel(w.w, r2, c2, m_c, o.s1, o.n1, o.x1)];
      __builtin_nontemporal_store(out, &y4[idx[j]]);
    }
  }
}

extern "C" void kernel_launch(void* const* d_in, const int* in_sizes, int n_in,
                              void* d_out, int out_size, void* d_ws, size_t ws_size,
                              hipStream_t stream) {
  const float4* x4      = (const float4*)d_in[0];
  const float* weight   = (const float*)d_in[1];
  const float* bias     = (const float*)d_in[2];
  const float* run_mean = (const float*)d_in[3];
  const float* run_var  = (const float*)d_in[4];
  natf4* y4 = (natf4*)d_out;

  float* w = (float*)d_ws;
  float* psum = w;                       // 1024 f32
  float* pmin = w + 1024;                // 1024 f32
  float* pmax = w + 2048;                // 1024 f32
  uint32_t* pk  = (uint32_t*)(w + 3072); // 1024 u32
  uint32_t* pk2 = (uint32_t*)(w + 4096); // 1024 u32

  dim3 grid(C_CH, 4), blk(256);
  void* args[] = {(void*)&x4, (void*)&weight, (void*)&bias, (void*)&run_mean,
                  (void*)&run_var, (void*)&y4, (void*)&psum, (void*)&pmin,
                  (void*)&pmax, (void*)&pk, (void*)&pk2};
  hipError_t err = hipLaunchCooperativeKernel((const void*)k_fused, grid, blk,
                                              args, 0, stream);
  if (err != hipSuccess) {
    // fallback: 3-kernel path (identical math)
    k_p1<<<grid, blk, 0, stream>>>(x4, psum, pmin, pmax);
    k_p2<<<grid, blk, 0, stream>>>(x4, psum, pmin, pmax, run_mean, pk, pk2);
    k_p3<<<grid, blk, 0, stream>>>(x4, psum, pmin, pmax, pk, pk2,
                                   run_mean, run_var, weight, bias, y4);
  }
}

// Round 6
// 381.641 us; speedup vs baseline: 1.4465x; 1.4465x over previous
//
#include <hip/hip_runtime.h>
#include <stdint.h>

// QuantizedBatchNorm (k=8 fake-quant, training forward), NCHW = [64,256,56,56] f32.
//
// 3-kernel schedule (deterministic, no atomics), grid 256ch x 4 splits x 256 thr:
//  K1: read x -> per-(c,s) partial {sum, min, max}
//  K2: prologue = redundant S1 (mean quant + ctr quant params via monotone
//      extremes); main = read x (L3-hot after K1), fast fma quant level k
//      (exact __fdiv_rn fallback near floor boundaries), EXACT integer
//      {sum k, sum k^2}, store packed k (uint8, 51 MB, L3-allocating)
//  K3: prologue = S1+S2 (exact var from integer sums -> inv_den/xn/y quant
//      params -> 256-entry per-channel y-LUT in LDS); main = read kq (51 MB,
//      L3-resident), y = lut[k], nontemporal store (205 MB can't evict kq)
// K3 never touches x -> robust to y-write L3 pollution (round-5 lesson:
// x re-reads were only ~50% L3-hit).
// All ref-visible elementwise math uses __f*_rn sequences identical to numpy.

#define C_CH 256
#define P4 784                 // float4 per plane (HW/4)
#define P16 196                // uint4-groups (4 float4 = 16 elems) per plane
#define PLANE_STRIDE 200704    // float4 stride between planes at fixed c (256*784)
#define KPLANE_STRIDE 50176    // uint4 stride between planes at fixed c
#define NHW_F 200704.0f
#define NHW_D 200704.0
#define TOLB 1e-3f

typedef float natf4 __attribute__((ext_vector_type(4)));

__device__ __forceinline__ float fq(float x, float sc, float qn, float qx) {
  if (sc == 0.0f) return x;                                   // range==0 passthrough
  float cs = __fsub_rn(fminf(fmaxf(x, qn), qx), qn);
  float f  = floorf(__fadd_rn(__fdiv_rn(cs, sc), 0.5f));
  return __fadd_rn(__fmul_rn(f, sc), qn);
}

__device__ __forceinline__ void qparams(float amax, float& sc, float& qn, float& qx) {
  sc = __fdiv_rn(__fmul_rn(2.0f, amax), 255.0f);
  qn = __fmul_rn(-128.0f, sc);                                // nzp = round(127.5) = 128
  qx = __fmul_rn(127.0f, sc);
}

__device__ __forceinline__ float block_max(float v, float* buf4) {
  #pragma unroll
  for (int m = 1; m <= 32; m <<= 1) v = fmaxf(v, __shfl_xor(v, m, 64));
  if ((threadIdx.x & 63) == 0) buf4[threadIdx.x >> 6] = v;
  __syncthreads();
  float r = fmaxf(fmaxf(buf4[0], buf4[1]), fmaxf(buf4[2], buf4[3]));
  __syncthreads();
  return r;
}

// Fast quant level: q ~= (x - m - n1)/s1 via fma; exact __fdiv_rn ref-sequence
// fallback when within TOLB of a floor boundary (|fast-true| <= ~1e-4 << TOLB).
__device__ __forceinline__ uint32_t qlevel(float xv, float r2, float c2,
    float m, float s1, float n1, float x1) {
  float q = fmaf(xv, r2, c2);
  q = fminf(fmaxf(q, 0.0f), 255.0f);
  const float qh = __fadd_rn(q, 0.5f);
  float fl = floorf(qh);
  const float d = __fsub_rn(qh, fl);
  if (__builtin_expect(fminf(d, __fsub_rn(1.0f, d)) < TOLB, 0)) {
    const float tt = __fsub_rn(xv, m);
    const float cs = __fsub_rn(fminf(fmaxf(tt, n1), x1), n1);
    fl = floorf(__fadd_rn(__fdiv_rn(cs, s1), 0.5f));
  }
  return (uint32_t)fl;                                        // in [0,255]
}

// Redundant S1 (thread t <-> channel t; identical in every block).
struct S1Out { float meanc, tmax, tmin, s1, n1, x1; };

__device__ __forceinline__ void s1_compute(const float* __restrict__ psum,
    const float* __restrict__ pmin, const float* __restrict__ pmax,
    const float* __restrict__ run_mean, float* buf4, S1Out& o) {
  const int t = threadIdx.x;
  float sum = __fadd_rn(__fadd_rn(__fadd_rn(psum[4*t], psum[4*t+1]), psum[4*t+2]), psum[4*t+3]);
  float mn = fminf(fminf(pmin[4*t], pmin[4*t+1]), fminf(pmin[4*t+2], pmin[4*t+3]));
  float mx = fmaxf(fmaxf(pmax[4*t], pmax[4*t+1]), fmaxf(pmax[4*t+2], pmax[4*t+3]));
  const float new_mean = __fdiv_rn(sum, NHW_F);
  const float mp = __fadd_rn(__fmul_rn(0.875f, run_mean[t]), __fmul_rn(0.125f, new_mean));
  const float am = block_max(fabsf(mp), buf4);
  float scm, qnm, qxm; qparams(am, scm, qnm, qxm);
  o.meanc = fq(mp, scm, qnm, qxm);
  o.tmax = __fsub_rn(mx, o.meanc);   // (x - mean_c) monotone in x: extremes attained
  o.tmin = __fsub_rn(mn, o.meanc);
  const float a1 = block_max(fmaxf(fabsf(o.tmax), fabsf(o.tmin)), buf4);
  qparams(a1, o.s1, o.n1, o.x1);
}

// S2 body (thread t <-> channel t): exact var from integer sums -> LUT.
__device__ __forceinline__ void s2_and_lut(const S1Out& o,
    const uint32_t* __restrict__ pk, const uint32_t* __restrict__ pk2,
    const float* __restrict__ run_var, const float* __restrict__ weight,
    const float* __restrict__ bias, float* buf4, float* bc, float* lut, int c) {
  const int t = threadIdx.x;
  // sum(ctr^2) = s1^2 * (sum k^2 - 256 sum k + 16384*N)   (exact integers)
  const unsigned long long ssq = (unsigned long long)pk2[4*t] + pk2[4*t+1]
                               + pk2[4*t+2] + pk2[4*t+3];
  const unsigned int skc = pk[4*t] + pk[4*t+1] + pk[4*t+2] + pk[4*t+3];
  const double s1d = (double)o.s1;
  const double sum_ctr2 = s1d * s1d *
      ((double)ssq - 256.0 * (double)skc + 16384.0 * NHW_D);
  const float new_var = (float)(sum_ctr2 / NHW_D);
  const float vp = __fadd_rn(__fmul_rn(0.875f, run_var[t]), __fmul_rn(0.125f, new_var));
  const float av = block_max(fabsf(vp), buf4);
  float scv, qnv, qxv; qparams(av, scv, qnv, qxv);
  const float varc = fq(vp, scv, qnv, qxv);
  const float dp = __fsqrt_rn(__fadd_rn(varc, 1e-5f));
  const float ad = block_max(fabsf(dp), buf4);
  float scd, qnd, qxd; qparams(ad, scd, qnd, qxd);
  const float idc = fq(dp, scd, qnd, qxd);
  const float ctrmax = fq(o.tmax, o.s1, o.n1, o.x1);
  const float ctrmin = fq(o.tmin, o.s1, o.n1, o.x1);
  const float xpmax = __fdiv_rn(ctrmax, idc);
  const float xpmin = __fdiv_rn(ctrmin, idc);
  const float a3 = block_max(fmaxf(fabsf(xpmax), fabsf(xpmin)), buf4);
  float s3, n3, x3; qparams(a3, s3, n3, x3);
  const float xnmax = fq(xpmax, s3, n3, x3);
  const float xnmin = fq(xpmin, s3, n3, x3);
  const float wv = weight[t];
  const float aw = block_max(fabsf(wv), buf4);
  float scw, qnw, qxw; qparams(aw, scw, qnw, qxw);
  const float qw = fq(wv, scw, qnw, qxw);
  const float bv = bias[t];
  const float ab = block_max(fabsf(bv), buf4);
  float scb, qnb, qxb; qparams(ab, scb, qnb, qxb);
  const float qb = fq(bv, scb, qnb, qxb);                     // bias==0 -> passthrough
  const float e1 = __fadd_rn(__fmul_rn(qw, xnmax), qb);
  const float e2 = __fadd_rn(__fmul_rn(qw, xnmin), qb);
  const float a4 = block_max(fmaxf(fabsf(e1), fabsf(e2)), buf4);
  float s4, n4, x4q; qparams(a4, s4, n4, x4q);
  if (t == c) { bc[0] = idc; bc[1] = qw; bc[2] = qb; }
  __syncthreads();
  const float idc_c = bc[0], qw_c = bc[1], qb_c = bc[2];
  const float ctr_t = __fadd_rn(__fmul_rn((float)t, o.s1), o.n1);
  const float xn_t = fq(__fdiv_rn(ctr_t, idc_c), s3, n3, x3);
  lut[t] = fq(__fadd_rn(__fmul_rn(qw_c, xn_t), qb_c), s4, n4, x4q);
  __syncthreads();
}

// ---------------- K1: per-channel partial sum/min/max ----------------
__global__ __launch_bounds__(256) void k_p1(const float4* __restrict__ x4,
    float* __restrict__ psum, float* __restrict__ pmin, float* __restrict__ pmax) {
  const int c = blockIdx.x, s = blockIdx.y, t = threadIdx.x;
  const int B0 = (s * 16 * C_CH + c) * P4;
  float sum = 0.0f, mn = INFINITY, mx = -INFINITY;
  #pragma unroll 1
  for (int g = 0; g < 7; ++g) {
    float4 v[7];
    #pragma unroll
    for (int j = 0; j < 7; ++j) {
      const int u = t + 256 * (7 * g + j);
      v[j] = x4[B0 + (u / P4) * PLANE_STRIDE + (u % P4)];
    }
    #pragma unroll
    for (int j = 0; j < 7; ++j) {
      const float4 w = v[j];
      sum = __fadd_rn(sum, __fadd_rn(__fadd_rn(w.x, w.y), __fadd_rn(w.z, w.w)));
      mn = fminf(mn, fminf(fminf(w.x, w.y), fminf(w.z, w.w)));
      mx = fmaxf(mx, fmaxf(fmaxf(w.x, w.y), fmaxf(w.z, w.w)));
    }
  }
  #pragma unroll
  for (int m = 1; m <= 32; m <<= 1) {
    sum = __fadd_rn(sum, __shfl_xor(sum, m, 64));
    mn = fminf(mn, __shfl_xor(mn, m, 64));
    mx = fmaxf(mx, __shfl_xor(mx, m, 64));
  }
  __shared__ float red[12];
  const int w_ = t >> 6;
  if ((t & 63) == 0) { red[w_] = sum; red[4 + w_] = mn; red[8 + w_] = mx; }
  __syncthreads();
  if (t == 0) {
    const int idx = c * 4 + s;
    psum[idx] = __fadd_rn(__fadd_rn(__fadd_rn(red[0], red[1]), red[2]), red[3]);
    pmin[idx] = fminf(fminf(red[4], red[5]), fminf(red[6], red[7]));
    pmax[idx] = fmaxf(fmaxf(red[8], red[9]), fmaxf(red[10], red[11]));
  }
}

// ---------------- K2: S1 prologue + int sums + packed k store ----------------
__global__ __launch_bounds__(256) void k_p2(const float4* __restrict__ x4,
    uint4* __restrict__ kq4,
    const float* __restrict__ psum, const float* __restrict__ pmin,
    const float* __restrict__ pmax, const float* __restrict__ run_mean,
    uint32_t* __restrict__ pk, uint32_t* __restrict__ pk2) {
  __shared__ float buf4[4];
  __shared__ float bc[1];
  const int c = blockIdx.x, s = blockIdx.y, t = threadIdx.x;
  S1Out o; s1_compute(psum, pmin, pmax, run_mean, buf4, o);
  if (t == c) bc[0] = o.meanc;
  __syncthreads();
  const float m_c = bc[0];
  const double rd = 1.0 / (double)o.s1;
  const float r2 = (float)rd;
  const float c2 = (float)((-(double)m_c - (double)o.n1) * rd);
  const int B0 = (s * 16 * C_CH + c) * P4;
  const int KB0 = (s * 16 * C_CH + c) * P16;
  int sk = 0, sk2 = 0;   // per-thread exact: sk<=5.3e4, sk2<=1.36e7
  #pragma unroll 1
  for (int mm = 0; mm < 6; ++mm) {                 // groups t+256*(2mm), t+256*(2mm+1)
    float4 v[8]; int pl[2], sl[2];
    #pragma unroll
    for (int h = 0; h < 2; ++h) {
      const int g = t + 256 * (2 * mm + h);
      pl[h] = g / P16; sl[h] = g - pl[h] * P16;
      const float4* p = x4 + B0 + pl[h] * PLANE_STRIDE + 4 * sl[h];
      v[4*h+0] = p[0]; v[4*h+1] = p[1]; v[4*h+2] = p[2]; v[4*h+3] = p[3];
    }
    #pragma unroll
    for (int h = 0; h < 2; ++h) {
      uint32_t kw[4];
      #pragma unroll
      for (int q = 0; q < 4; ++q) {
        const float4 w = v[4*h+q];
        const float vv[4] = {w.x, w.y, w.z, w.w};
        uint32_t acc = 0;
        #pragma unroll
        for (int e = 0; e < 4; ++e) {
          const uint32_t k = qlevel(vv[e], r2, c2, m_c, o.s1, o.n1, o.x1);
          sk += (int)k; sk2 += (int)(k * k);
          acc |= k << (8 * e);
        }
        kw[q] = acc;
      }
      uint4 st; st.x = kw[0]; st.y = kw[1]; st.z = kw[2]; st.w = kw[3];
      kq4[KB0 + pl[h] * KPLANE_STRIDE + sl[h]] = st;   // regular store: L3-allocate
    }
  }
  if (t < 64) {                                     // tail: group 3072+t
    const int g = 3072 + t;
    const int plane = g / P16, slot = g - plane * P16;
    const float4* p = x4 + B0 + plane * PLANE_STRIDE + 4 * slot;
    uint32_t kw[4];
    #pragma unroll
    for (int q = 0; q < 4; ++q) {
      const float4 w = p[q];
      const float vv[4] = {w.x, w.y, w.z, w.w};
      uint32_t acc = 0;
      #pragma unroll
      for (int e = 0; e < 4; ++e) {
        const uint32_t k = qlevel(vv[e], r2, c2, m_c, o.s1, o.n1, o.x1);
        sk += (int)k; sk2 += (int)(k * k);
        acc |= k << (8 * e);
      }
      kw[q] = acc;
    }
    uint4 st; st.x = kw[0]; st.y = kw[1]; st.z = kw[2]; st.w = kw[3];
    kq4[KB0 + plane * KPLANE_STRIDE + slot] = st;
  }
  #pragma unroll
  for (int m = 1; m <= 32; m <<= 1) {   // wave sums: sk2 <= 8.7e8 fits int
    sk += __shfl_xor(sk, m, 64);
    sk2 += __shfl_xor(sk2, m, 64);
  }
  __shared__ uint32_t ired[8];
  const int w_ = t >> 6;
  if ((t & 63) == 0) { ired[w_] = (uint32_t)sk; ired[4 + w_] = (uint32_t)sk2; }
  __syncthreads();
  if (t == 0) {
    const int idx = c * 4 + s;
    pk[idx]  = ired[0] + ired[1] + ired[2] + ired[3];          // <=1.4e7
    pk2[idx] = ired[4] + ired[5] + ired[6] + ired[7];          // <=3.3e9, fits u32
  }
}

// ---------------- K3: S1+S2 prologue + y = lut[kq], NT store ----------------
__global__ __launch_bounds__(256) void k_p3(const uint4* __restrict__ kq4,
    const float* __restrict__ psum, const float* __restrict__ pmin,
    const float* __restrict__ pmax, const uint32_t* __restrict__ pk,
    const uint32_t* __restrict__ pk2,
    const float* __restrict__ run_mean, const float* __restrict__ run_var,
    const float* __restrict__ weight, const float* __restrict__ bias,
    natf4* __restrict__ y4) {
  __shared__ float buf4[4];
  __shared__ float bc[4];
  __shared__ float lut[256];
  const int c = blockIdx.x, s = blockIdx.y, t = threadIdx.x;
  S1Out o; s1_compute(psum, pmin, pmax, run_mean, buf4, o);
  s2_and_lut(o, pk, pk2, run_var, weight, bias, buf4, bc, lut, c);
  const int B0 = (s * 16 * C_CH + c) * P4;
  const int KB0 = (s * 16 * C_CH + c) * P16;
  #pragma unroll 1
  for (int mm = 0; mm < 6; ++mm) {
    uint4 kk[2]; int pl[2], sl[2];
    #pragma unroll
    for (int h = 0; h < 2; ++h) {
      const int g = t + 256 * (2 * mm + h);
      pl[h] = g / P16; sl[h] = g - pl[h] * P16;
      kk[h] = kq4[KB0 + pl[h] * KPLANE_STRIDE + sl[h]];
    }
    #pragma unroll
    for (int h = 0; h < 2; ++h) {
      natf4* yp = y4 + B0 + pl[h] * PLANE_STRIDE + 4 * sl[h];
      const uint32_t ka[4] = {kk[h].x, kk[h].y, kk[h].z, kk[h].w};
      #pragma unroll
      for (int q = 0; q < 4; ++q) {
        const uint32_t w = ka[q];
        natf4 out;
        out.x = lut[w & 255]; out.y = lut[(w >> 8) & 255];
        out.z = lut[(w >> 16) & 255]; out.w = lut[w >> 24];
        __builtin_nontemporal_store(out, &yp[q]);   // don't evict kq from L3
      }
    }
  }
  if (t < 64) {                                     // tail: group 3072+t
    const int g = 3072 + t;
    const int plane = g / P16, slot = g - plane * P16;
    const uint4 kk = kq4[KB0 + plane * KPLANE_STRIDE + slot];
    natf4* yp = y4 + B0 + plane * PLANE_STRIDE + 4 * slot;
    const uint32_t ka[4] = {kk.x, kk.y, kk.z, kk.w};
    #pragma unroll
    for (int q = 0; q < 4; ++q) {
      const uint32_t w = ka[q];
      natf4 out;
      out.x = lut[w & 255]; out.y = lut[(w >> 8) & 255];
      out.z = lut[(w >> 16) & 255]; out.w = lut[w >> 24];
      __builtin_nontemporal_store(out, &yp[q]);
    }
  }
}

extern "C" void kernel_launch(void* const* d_in, const int* in_sizes, int n_in,
                              void* d_out, int out_size, void* d_ws, size_t ws_size,
                              hipStream_t stream) {
  const float4* x4      = (const float4*)d_in[0];
  const float* weight   = (const float*)d_in[1];
  const float* bias     = (const float*)d_in[2];
  const float* run_mean = (const float*)d_in[3];
  const float* run_var  = (const float*)d_in[4];
  natf4* y4 = (natf4*)d_out;

  float* w = (float*)d_ws;
  float* psum = w;                       // bytes     0.. 4095
  float* pmin = w + 1024;                //        4096.. 8191
  float* pmax = w + 2048;                //        8192..12287
  uint32_t* pk  = (uint32_t*)(w + 3072); //       12288..16383
  uint32_t* pk2 = (uint32_t*)(w + 4096); //       16384..20479
  uint4* kq4 = (uint4*)((char*)d_ws + 32768);  // 51,380,224 bytes (ws is ~800 MB)

  dim3 grid(C_CH, 4), blk(256);
  k_p1<<<grid, blk, 0, stream>>>(x4, psum, pmin, pmax);
  k_p2<<<grid, blk, 0, stream>>>(x4, kq4, psum, pmin, pmax, run_mean, pk, pk2);
  k_p3<<<grid, blk, 0, stream>>>(kq4, psum, pmin, pmax, pk, pk2,
                                 run_mean, run_var, weight, bias, y4);
}

// Round 7
// 117.632 us; speedup vs baseline: 4.6928x; 3.2444x over previous
//
#include <hip/hip_runtime.h>
#include <stdint.h>

// QuantizedBatchNorm (k=8 fake-quant, training forward), NCHW = [64,256,56,56] f32.
//
// 3-kernel schedule (deterministic, no atomics), grid 256ch x 4 splits x 256 thr:
//  K1: read x -> per-(c,s) partial {sum, min, max}
//  K2: prologue = redundant S1; main = read x (L3-hot), fast fma quant level k
//      (exact __fdiv_rn fallback near floor boundaries), EXACT integer
//      {sum k, sum k^2}, pack 4 levels -> 1 uint32 (same index as the float4),
//      coalesced store (51 MB, L3-allocating)
//  K3: prologue = S1+S2 (exact var from int sums -> y-LUT in LDS); main = read
//      kq uint32/lane (L3-resident), y = lut[k] float4/lane, NT store.
// COALESCING RULE (round-6 lesson): lane i <-> slot i, unit stride across
// lanes, 16B/lane stores = full 64B lines. 64B-chunk-per-thread caused 2.5x
// write amplification with NT partial lines.
// All ref-visible elementwise math uses __f*_rn sequences identical to numpy.

#define C_CH 256
#define P4 784                 // float4 per plane (HW/4)
#define PLANE_STRIDE 200704    // float4 stride between planes at fixed c (256*784)
#define NHW_F 200704.0f
#define NHW_D 200704.0
#define TOLB 1e-3f

typedef float natf4 __attribute__((ext_vector_type(4)));

__device__ __forceinline__ float fq(float x, float sc, float qn, float qx) {
  if (sc == 0.0f) return x;                                   // range==0 passthrough
  float cs = __fsub_rn(fminf(fmaxf(x, qn), qx), qn);
  float f  = floorf(__fadd_rn(__fdiv_rn(cs, sc), 0.5f));
  return __fadd_rn(__fmul_rn(f, sc), qn);
}

__device__ __forceinline__ void qparams(float amax, float& sc, float& qn, float& qx) {
  sc = __fdiv_rn(__fmul_rn(2.0f, amax), 255.0f);
  qn = __fmul_rn(-128.0f, sc);                                // nzp = round(127.5) = 128
  qx = __fmul_rn(127.0f, sc);
}

__device__ __forceinline__ float block_max(float v, float* buf4) {
  #pragma unroll
  for (int m = 1; m <= 32; m <<= 1) v = fmaxf(v, __shfl_xor(v, m, 64));
  if ((threadIdx.x & 63) == 0) buf4[threadIdx.x >> 6] = v;
  __syncthreads();
  float r = fmaxf(fmaxf(buf4[0], buf4[1]), fmaxf(buf4[2], buf4[3]));
  __syncthreads();
  return r;
}

// Fast quant level: q ~= (x - m - n1)/s1 via fma; exact __fdiv_rn ref-sequence
// fallback when within TOLB of a floor boundary (|fast-true| <= ~1e-4 << TOLB).
__device__ __forceinline__ uint32_t qlevel(float xv, float r2, float c2,
    float m, float s1, float n1, float x1) {
  float q = fmaf(xv, r2, c2);
  q = fminf(fmaxf(q, 0.0f), 255.0f);
  const float qh = __fadd_rn(q, 0.5f);
  float fl = floorf(qh);
  const float d = __fsub_rn(qh, fl);
  if (__builtin_expect(fminf(d, __fsub_rn(1.0f, d)) < TOLB, 0)) {
    const float tt = __fsub_rn(xv, m);
    const float cs = __fsub_rn(fminf(fmaxf(tt, n1), x1), n1);
    fl = floorf(__fadd_rn(__fdiv_rn(cs, s1), 0.5f));
  }
  return (uint32_t)fl;                                        // in [0,255]
}

// Redundant S1 (thread t <-> channel t; identical in every block).
struct S1Out { float meanc, tmax, tmin, s1, n1, x1; };

__device__ __forceinline__ void s1_compute(const float* __restrict__ psum,
    const float* __restrict__ pmin, const float* __restrict__ pmax,
    const float* __restrict__ run_mean, float* buf4, S1Out& o) {
  const int t = threadIdx.x;
  float sum = __fadd_rn(__fadd_rn(__fadd_rn(psum[4*t], psum[4*t+1]), psum[4*t+2]), psum[4*t+3]);
  float mn = fminf(fminf(pmin[4*t], pmin[4*t+1]), fminf(pmin[4*t+2], pmin[4*t+3]));
  float mx = fmaxf(fmaxf(pmax[4*t], pmax[4*t+1]), fmaxf(pmax[4*t+2], pmax[4*t+3]));
  const float new_mean = __fdiv_rn(sum, NHW_F);
  const float mp = __fadd_rn(__fmul_rn(0.875f, run_mean[t]), __fmul_rn(0.125f, new_mean));
  const float am = block_max(fabsf(mp), buf4);
  float scm, qnm, qxm; qparams(am, scm, qnm, qxm);
  o.meanc = fq(mp, scm, qnm, qxm);
  o.tmax = __fsub_rn(mx, o.meanc);   // (x - mean_c) monotone in x: extremes attained
  o.tmin = __fsub_rn(mn, o.meanc);
  const float a1 = block_max(fmaxf(fabsf(o.tmax), fabsf(o.tmin)), buf4);
  qparams(a1, o.s1, o.n1, o.x1);
}

// S2 body (thread t <-> channel t): exact var from integer sums -> LUT.
__device__ __forceinline__ void s2_and_lut(const S1Out& o,
    const uint32_t* __restrict__ pk, const uint32_t* __restrict__ pk2,
    const float* __restrict__ run_var, const float* __restrict__ weight,
    const float* __restrict__ bias, float* buf4, float* bc, float* lut, int c) {
  const int t = threadIdx.x;
  // sum(ctr^2) = s1^2 * (sum k^2 - 256 sum k + 16384*N)   (exact integers)
  const unsigned long long ssq = (unsigned long long)pk2[4*t] + pk2[4*t+1]
                               + pk2[4*t+2] + pk2[4*t+3];
  const unsigned int skc = pk[4*t] + pk[4*t+1] + pk[4*t+2] + pk[4*t+3];
  const double s1d = (double)o.s1;
  const double sum_ctr2 = s1d * s1d *
      ((double)ssq - 256.0 * (double)skc + 16384.0 * NHW_D);
  const float new_var = (float)(sum_ctr2 / NHW_D);
  const float vp = __fadd_rn(__fmul_rn(0.875f, run_var[t]), __fmul_rn(0.125f, new_var));
  const float av = block_max(fabsf(vp), buf4);
  float scv, qnv, qxv; qparams(av, scv, qnv, qxv);
  const float varc = fq(vp, scv, qnv, qxv);
  const float dp = __fsqrt_rn(__fadd_rn(varc, 1e-5f));
  const float ad = block_max(fabsf(dp), buf4);
  float scd, qnd, qxd; qparams(ad, scd, qnd, qxd);
  const float idc = fq(dp, scd, qnd, qxd);
  const float ctrmax = fq(o.tmax, o.s1, o.n1, o.x1);
  const float ctrmin = fq(o.tmin, o.s1, o.n1, o.x1);
  const float xpmax = __fdiv_rn(ctrmax, idc);
  const float xpmin = __fdiv_rn(ctrmin, idc);
  const float a3 = block_max(fmaxf(fabsf(xpmax), fabsf(xpmin)), buf4);
  float s3, n3, x3; qparams(a3, s3, n3, x3);
  const float xnmax = fq(xpmax, s3, n3, x3);
  const float xnmin = fq(xpmin, s3, n3, x3);
  const float wv = weight[t];
  const float aw = block_max(fabsf(wv), buf4);
  float scw, qnw, qxw; qparams(aw, scw, qnw, qxw);
  const float qw = fq(wv, scw, qnw, qxw);
  const float bv = bias[t];
  const float ab = block_max(fabsf(bv), buf4);
  float scb, qnb, qxb; qparams(ab, scb, qnb, qxb);
  const float qb = fq(bv, scb, qnb, qxb);                     // bias==0 -> passthrough
  const float e1 = __fadd_rn(__fmul_rn(qw, xnmax), qb);
  const float e2 = __fadd_rn(__fmul_rn(qw, xnmin), qb);
  const float a4 = block_max(fmaxf(fabsf(e1), fabsf(e2)), buf4);
  float s4, n4, x4q; qparams(a4, s4, n4, x4q);
  if (t == c) { bc[0] = idc; bc[1] = qw; bc[2] = qb; }
  __syncthreads();
  const float idc_c = bc[0], qw_c = bc[1], qb_c = bc[2];
  const float ctr_t = __fadd_rn(__fmul_rn((float)t, o.s1), o.n1);
  const float xn_t = fq(__fdiv_rn(ctr_t, idc_c), s3, n3, x3);
  lut[t] = fq(__fadd_rn(__fmul_rn(qw_c, xn_t), qb_c), s4, n4, x4q);
  __syncthreads();
}

// ---------------- K1: per-channel partial sum/min/max ----------------
__global__ __launch_bounds__(256) void k_p1(const float4* __restrict__ x4,
    float* __restrict__ psum, float* __restrict__ pmin, float* __restrict__ pmax) {
  const int c = blockIdx.x, s = blockIdx.y, t = threadIdx.x;
  const int B0 = (s * 16 * C_CH + c) * P4;
  float sum = 0.0f, mn = INFINITY, mx = -INFINITY;
  #pragma unroll 1
  for (int g = 0; g < 7; ++g) {
    float4 v[7];
    #pragma unroll
    for (int j = 0; j < 7; ++j) {
      const int u = t + 256 * (7 * g + j);
      v[j] = x4[B0 + (u / P4) * PLANE_STRIDE + (u % P4)];
    }
    #pragma unroll
    for (int j = 0; j < 7; ++j) {
      const float4 w = v[j];
      sum = __fadd_rn(sum, __fadd_rn(__fadd_rn(w.x, w.y), __fadd_rn(w.z, w.w)));
      mn = fminf(mn, fminf(fminf(w.x, w.y), fminf(w.z, w.w)));
      mx = fmaxf(mx, fmaxf(fmaxf(w.x, w.y), fmaxf(w.z, w.w)));
    }
  }
  #pragma unroll
  for (int m = 1; m <= 32; m <<= 1) {
    sum = __fadd_rn(sum, __shfl_xor(sum, m, 64));
    mn = fminf(mn, __shfl_xor(mn, m, 64));
    mx = fmaxf(mx, __shfl_xor(mx, m, 64));
  }
  __shared__ float red[12];
  const int w_ = t >> 6;
  if ((t & 63) == 0) { red[w_] = sum; red[4 + w_] = mn; red[8 + w_] = mx; }
  __syncthreads();
  if (t == 0) {
    const int idx = c * 4 + s;
    psum[idx] = __fadd_rn(__fadd_rn(__fadd_rn(red[0], red[1]), red[2]), red[3]);
    pmin[idx] = fminf(fminf(red[4], red[5]), fminf(red[6], red[7]));
    pmax[idx] = fmaxf(fmaxf(red[8], red[9]), fmaxf(red[10], red[11]));
  }
}

// ---------------- K2: S1 prologue + int sums + packed-k coalesced store ----------------
__global__ __launch_bounds__(256) void k_p2(const float4* __restrict__ x4,
    uint32_t* __restrict__ kq32,
    const float* __restrict__ psum, const float* __restrict__ pmin,
    const float* __restrict__ pmax, const float* __restrict__ run_mean,
    uint32_t* __restrict__ pk, uint32_t* __restrict__ pk2) {
  __shared__ float buf4[4];
  __shared__ float bc[1];
  const int c = blockIdx.x, s = blockIdx.y, t = threadIdx.x;
  S1Out o; s1_compute(psum, pmin, pmax, run_mean, buf4, o);
  if (t == c) bc[0] = o.meanc;
  __syncthreads();
  const float m_c = bc[0];
  const double rd = 1.0 / (double)o.s1;
  const float r2 = (float)rd;
  const float c2 = (float)((-(double)m_c - (double)o.n1) * rd);
  const int B0 = (s * 16 * C_CH + c) * P4;
  int sk = 0, sk2 = 0;   // per-thread exact: sk<=5e4, sk2<=1.27e7
  #pragma unroll 1
  for (int g = 0; g < 7; ++g) {
    float4 v[7]; int idx[7];
    #pragma unroll
    for (int j = 0; j < 7; ++j) {
      const int u = t + 256 * (7 * g + j);
      idx[j] = B0 + (u / P4) * PLANE_STRIDE + (u % P4);
      v[j] = x4[idx[j]];                                      // 16B/lane coalesced
    }
    #pragma unroll
    for (int j = 0; j < 7; ++j) {
      const float4 w = v[j];
      const float vv[4] = {w.x, w.y, w.z, w.w};
      uint32_t acc = 0;
      #pragma unroll
      for (int e = 0; e < 4; ++e) {
        const uint32_t k = qlevel(vv[e], r2, c2, m_c, o.s1, o.n1, o.x1);
        sk += (int)k; sk2 += (int)(k * k);
        acc |= k << (8 * e);
      }
      kq32[idx[j]] = acc;                                     // 4B/lane coalesced
    }
  }
  #pragma unroll
  for (int m = 1; m <= 32; m <<= 1) {   // wave sums: sk2 <= 8.2e8 fits int
    sk += __shfl_xor(sk, m, 64);
    sk2 += __shfl_xor(sk2, m, 64);
  }
  __shared__ uint32_t ired[8];
  const int w_ = t >> 6;
  if ((t & 63) == 0) { ired[w_] = (uint32_t)sk; ired[4 + w_] = (uint32_t)sk2; }
  __syncthreads();
  if (t == 0) {
    const int idx = c * 4 + s;
    pk[idx]  = ired[0] + ired[1] + ired[2] + ired[3];          // <=1.3e7
    pk2[idx] = ired[4] + ired[5] + ired[6] + ired[7];          // <=3.27e9, fits u32
  }
}

// ---------------- K3: S1+S2 prologue + y = lut[kq], coalesced NT store ----------------
__global__ __launch_bounds__(256) void k_p3(const uint32_t* __restrict__ kq32,
    const float* __restrict__ psum, const float* __restrict__ pmin,
    const float* __restrict__ pmax, const uint32_t* __restrict__ pk,
    const uint32_t* __restrict__ pk2,
    const float* __restrict__ run_mean, const float* __restrict__ run_var,
    const float* __restrict__ weight, const float* __restrict__ bias,
    natf4* __restrict__ y4) {
  __shared__ float buf4[4];
  __shared__ float bc[4];
  __shared__ float lut[256];
  const int c = blockIdx.x, s = blockIdx.y, t = threadIdx.x;
  S1Out o; s1_compute(psum, pmin, pmax, run_mean, buf4, o);
  s2_and_lut(o, pk, pk2, run_var, weight, bias, buf4, bc, lut, c);
  const int B0 = (s * 16 * C_CH + c) * P4;
  #pragma unroll 1
  for (int g = 0; g < 7; ++g) {
    uint32_t kk[7]; int idx[7];
    #pragma unroll
    for (int j = 0; j < 7; ++j) {
      const int u = t + 256 * (7 * g + j);
      idx[j] = B0 + (u / P4) * PLANE_STRIDE + (u % P4);
      kk[j] = kq32[idx[j]];                                   // 4B/lane coalesced, L3-hot
    }
    #pragma unroll
    for (int j = 0; j < 7; ++j) {
      const uint32_t w = kk[j];
      natf4 out;
      out.x = lut[w & 255]; out.y = lut[(w >> 8) & 255];
      out.z = lut[(w >> 16) & 255]; out.w = lut[w >> 24];
      __builtin_nontemporal_store(out, &y4[idx[j]]);          // 16B/lane: full lines
    }
  }
}

extern "C" void kernel_launch(void* const* d_in, const int* in_sizes, int n_in,
                              void* d_out, int out_size, void* d_ws, size_t ws_size,
                              hipStream_t stream) {
  const float4* x4      = (const float4*)d_in[0];
  const float* weight   = (const float*)d_in[1];
  const float* bias     = (const float*)d_in[2];
  const float* run_mean = (const float*)d_in[3];
  const float* run_var  = (const float*)d_in[4];
  natf4* y4 = (natf4*)d_out;

  float* w = (float*)d_ws;
  float* psum = w;                       // bytes     0.. 4095
  float* pmin = w + 1024;                //        4096.. 8191
  float* pmax = w + 2048;                //        8192..12287
  uint32_t* pk  = (uint32_t*)(w + 3072); //       12288..16383
  uint32_t* pk2 = (uint32_t*)(w + 4096); //       16384..20479
  uint32_t* kq32 = (uint32_t*)((char*)d_ws + 32768);  // 51,380,224 bytes

  dim3 grid(C_CH, 4), blk(256);
  k_p1<<<grid, blk, 0, stream>>>(x4, psum, pmin, pmax);
  k_p2<<<grid, blk, 0, stream>>>(x4, kq32, psum, pmin, pmax, run_mean, pk, pk2);
  k_p3<<<grid, blk, 0, stream>>>(kq32, psum, pmin, pmax, pk, pk2,
                                 run_mean, run_var, weight, bias, y4);
}

// Round 8
// 117.563 us; speedup vs baseline: 4.6956x; 1.0006x over previous
//
#include <hip/hip_runtime.h>
#include <stdint.h>

// QuantizedBatchNorm (k=8 fake-quant, training forward), NCHW = [64,256,56,56] f32.
//
// 3-kernel schedule (deterministic, no atomics), grid 256ch x 4 splits x 256 thr:
//  K1: read x FORWARD -> per-(c,s) partial {sum, min, max}
//  K2: prologue = redundant S1; main = read x in REVERSE chunk order (zig-zag
//      scan: x+kq ~ 256.5 MB straddles the 256 MB L3; same-direction re-read is
//      the LRU worst case, reverse re-read starts on the freshest lines), fast
//      fma quant level k (exact __fdiv_rn fallback near floor boundaries),
//      EXACT integer {sum k, sum k^2}, pack 4 levels -> uint32, coalesced store
//  K3: prologue = S1+S2 (exact var from int sums -> per-channel y-LUT in LDS);
//      main = read kq FORWARD (K2 wrote high->low, freshest at low addrs),
//      y = lut[k] float4/lane, NT store (don't evict x/kq).
// COALESCING RULE (round-6 lesson): lane i <-> slot i, unit stride across
// lanes, 16B/lane stores = full 64B lines. Chunk order may be reversed freely
// (coalescing is per-instruction); per-thread element sets unchanged -> the
// integer k-stats and output are bit-identical to the forward version.
// All ref-visible elementwise math uses __f*_rn sequences identical to numpy.

#define C_CH 256
#define P4 784                 // float4 per plane (HW/4)
#define PLANE_STRIDE 200704    // float4 stride between planes at fixed c (256*784)
#define NHW_F 200704.0f
#define NHW_D 200704.0
#define TOLB 1e-3f

typedef float natf4 __attribute__((ext_vector_type(4)));

__device__ __forceinline__ float fq(float x, float sc, float qn, float qx) {
  if (sc == 0.0f) return x;                                   // range==0 passthrough
  float cs = __fsub_rn(fminf(fmaxf(x, qn), qx), qn);
  float f  = floorf(__fadd_rn(__fdiv_rn(cs, sc), 0.5f));
  return __fadd_rn(__fmul_rn(f, sc), qn);
}

__device__ __forceinline__ void qparams(float amax, float& sc, float& qn, float& qx) {
  sc = __fdiv_rn(__fmul_rn(2.0f, amax), 255.0f);
  qn = __fmul_rn(-128.0f, sc);                                // nzp = round(127.5) = 128
  qx = __fmul_rn(127.0f, sc);
}

__device__ __forceinline__ float block_max(float v, float* buf4) {
  #pragma unroll
  for (int m = 1; m <= 32; m <<= 1) v = fmaxf(v, __shfl_xor(v, m, 64));
  if ((threadIdx.x & 63) == 0) buf4[threadIdx.x >> 6] = v;
  __syncthreads();
  float r = fmaxf(fmaxf(buf4[0], buf4[1]), fmaxf(buf4[2], buf4[3]));
  __syncthreads();
  return r;
}

// Fast quant level: q ~= (x - m - n1)/s1 via fma; exact __fdiv_rn ref-sequence
// fallback when within TOLB of a floor boundary (|fast-true| <= ~1e-4 << TOLB).
__device__ __forceinline__ uint32_t qlevel(float xv, float r2, float c2,
    float m, float s1, float n1, float x1) {
  float q = fmaf(xv, r2, c2);
  q = fminf(fmaxf(q, 0.0f), 255.0f);
  const float qh = __fadd_rn(q, 0.5f);
  float fl = floorf(qh);
  const float d = __fsub_rn(qh, fl);
  if (__builtin_expect(fminf(d, __fsub_rn(1.0f, d)) < TOLB, 0)) {
    const float tt = __fsub_rn(xv, m);
    const float cs = __fsub_rn(fminf(fmaxf(tt, n1), x1), n1);
    fl = floorf(__fadd_rn(__fdiv_rn(cs, s1), 0.5f));
  }
  return (uint32_t)fl;                                        // in [0,255]
}

// Redundant S1 (thread t <-> channel t; identical in every block).
struct S1Out { float meanc, tmax, tmin, s1, n1, x1; };

__device__ __forceinline__ void s1_compute(const float* __restrict__ psum,
    const float* __restrict__ pmin, const float* __restrict__ pmax,
    const float* __restrict__ run_mean, float* buf4, S1Out& o) {
  const int t = threadIdx.x;
  float sum = __fadd_rn(__fadd_rn(__fadd_rn(psum[4*t], psum[4*t+1]), psum[4*t+2]), psum[4*t+3]);
  float mn = fminf(fminf(pmin[4*t], pmin[4*t+1]), fminf(pmin[4*t+2], pmin[4*t+3]));
  float mx = fmaxf(fmaxf(pmax[4*t], pmax[4*t+1]), fmaxf(pmax[4*t+2], pmax[4*t+3]));
  const float new_mean = __fdiv_rn(sum, NHW_F);
  const float mp = __fadd_rn(__fmul_rn(0.875f, run_mean[t]), __fmul_rn(0.125f, new_mean));
  const float am = block_max(fabsf(mp), buf4);
  float scm, qnm, qxm; qparams(am, scm, qnm, qxm);
  o.meanc = fq(mp, scm, qnm, qxm);
  o.tmax = __fsub_rn(mx, o.meanc);   // (x - mean_c) monotone in x: extremes attained
  o.tmin = __fsub_rn(mn, o.meanc);
  const float a1 = block_max(fmaxf(fabsf(o.tmax), fabsf(o.tmin)), buf4);
  qparams(a1, o.s1, o.n1, o.x1);
}

// S2 body (thread t <-> channel t): exact var from integer sums -> LUT.
__device__ __forceinline__ void s2_and_lut(const S1Out& o,
    const uint32_t* __restrict__ pk, const uint32_t* __restrict__ pk2,
    const float* __restrict__ run_var, const float* __restrict__ weight,
    const float* __restrict__ bias, float* buf4, float* bc, float* lut, int c) {
  const int t = threadIdx.x;
  // sum(ctr^2) = s1^2 * (sum k^2 - 256 sum k + 16384*N)   (exact integers)
  const unsigned long long ssq = (unsigned long long)pk2[4*t] + pk2[4*t+1]
                               + pk2[4*t+2] + pk2[4*t+3];
  const unsigned int skc = pk[4*t] + pk[4*t+1] + pk[4*t+2] + pk[4*t+3];
  const double s1d = (double)o.s1;
  const double sum_ctr2 = s1d * s1d *
      ((double)ssq - 256.0 * (double)skc + 16384.0 * NHW_D);
  const float new_var = (float)(sum_ctr2 / NHW_D);
  const float vp = __fadd_rn(__fmul_rn(0.875f, run_var[t]), __fmul_rn(0.125f, new_var));
  const float av = block_max(fabsf(vp), buf4);
  float scv, qnv, qxv; qparams(av, scv, qnv, qxv);
  const float varc = fq(vp, scv, qnv, qxv);
  const float dp = __fsqrt_rn(__fadd_rn(varc, 1e-5f));
  const float ad = block_max(fabsf(dp), buf4);
  float scd, qnd, qxd; qparams(ad, scd, qnd, qxd);
  const float idc = fq(dp, scd, qnd, qxd);
  const float ctrmax = fq(o.tmax, o.s1, o.n1, o.x1);
  const float ctrmin = fq(o.tmin, o.s1, o.n1, o.x1);
  const float xpmax = __fdiv_rn(ctrmax, idc);
  const float xpmin = __fdiv_rn(ctrmin, idc);
  const float a3 = block_max(fmaxf(fabsf(xpmax), fabsf(xpmin)), buf4);
  float s3, n3, x3; qparams(a3, s3, n3, x3);
  const float xnmax = fq(xpmax, s3, n3, x3);
  const float xnmin = fq(xpmin, s3, n3, x3);
  const float wv = weight[t];
  const float aw = block_max(fabsf(wv), buf4);
  float scw, qnw, qxw; qparams(aw, scw, qnw, qxw);
  const float qw = fq(wv, scw, qnw, qxw);
  const float bv = bias[t];
  const float ab = block_max(fabsf(bv), buf4);
  float scb, qnb, qxb; qparams(ab, scb, qnb, qxb);
  const float qb = fq(bv, scb, qnb, qxb);                     // bias==0 -> passthrough
  const float e1 = __fadd_rn(__fmul_rn(qw, xnmax), qb);
  const float e2 = __fadd_rn(__fmul_rn(qw, xnmin), qb);
  const float a4 = block_max(fmaxf(fabsf(e1), fabsf(e2)), buf4);
  float s4, n4, x4q; qparams(a4, s4, n4, x4q);
  if (t == c) { bc[0] = idc; bc[1] = qw; bc[2] = qb; }
  __syncthreads();
  const float idc_c = bc[0], qw_c = bc[1], qb_c = bc[2];
  const float ctr_t = __fadd_rn(__fmul_rn((float)t, o.s1), o.n1);
  const float xn_t = fq(__fdiv_rn(ctr_t, idc_c), s3, n3, x3);
  lut[t] = fq(__fadd_rn(__fmul_rn(qw_c, xn_t), qb_c), s4, n4, x4q);
  __syncthreads();
}

// ---------------- K1: per-channel partial sum/min/max (FORWARD sweep) ----------------
__global__ __launch_bounds__(256) void k_p1(const float4* __restrict__ x4,
    float* __restrict__ psum, float* __restrict__ pmin, float* __restrict__ pmax) {
  const int c = blockIdx.x, s = blockIdx.y, t = threadIdx.x;
  const int B0 = (s * 16 * C_CH + c) * P4;
  float sum = 0.0f, mn = INFINITY, mx = -INFINITY;
  #pragma unroll 1
  for (int g = 0; g < 7; ++g) {
    float4 v[7];
    #pragma unroll
    for (int j = 0; j < 7; ++j) {
      const int u = t + 256 * (7 * g + j);
      v[j] = x4[B0 + (u / P4) * PLANE_STRIDE + (u % P4)];
    }
    #pragma unroll
    for (int j = 0; j < 7; ++j) {
      const float4 w = v[j];
      sum = __fadd_rn(sum, __fadd_rn(__fadd_rn(w.x, w.y), __fadd_rn(w.z, w.w)));
      mn = fminf(mn, fminf(fminf(w.x, w.y), fminf(w.z, w.w)));
      mx = fmaxf(mx, fmaxf(fmaxf(w.x, w.y), fmaxf(w.z, w.w)));
    }
  }
  #pragma unroll
  for (int m = 1; m <= 32; m <<= 1) {
    sum = __fadd_rn(sum, __shfl_xor(sum, m, 64));
    mn = fminf(mn, __shfl_xor(mn, m, 64));
    mx = fmaxf(mx, __shfl_xor(mx, m, 64));
  }
  __shared__ float red[12];
  const int w_ = t >> 6;
  if ((t & 63) == 0) { red[w_] = sum; red[4 + w_] = mn; red[8 + w_] = mx; }
  __syncthreads();
  if (t == 0) {
    const int idx = c * 4 + s;
    psum[idx] = __fadd_rn(__fadd_rn(__fadd_rn(red[0], red[1]), red[2]), red[3]);
    pmin[idx] = fminf(fminf(red[4], red[5]), fminf(red[6], red[7]));
    pmax[idx] = fmaxf(fmaxf(red[8], red[9]), fmaxf(red[10], red[11]));
  }
}

// ---------------- K2: S1 prologue + int sums + packed-k store (REVERSE sweep) ----------------
__global__ __launch_bounds__(256) void k_p2(const float4* __restrict__ x4,
    uint32_t* __restrict__ kq32,
    const float* __restrict__ psum, const float* __restrict__ pmin,
    const float* __restrict__ pmax, const float* __restrict__ run_mean,
    uint32_t* __restrict__ pk, uint32_t* __restrict__ pk2) {
  __shared__ float buf4[4];
  __shared__ float bc[1];
  const int c = blockIdx.x, s = blockIdx.y, t = threadIdx.x;
  S1Out o; s1_compute(psum, pmin, pmax, run_mean, buf4, o);
  if (t == c) bc[0] = o.meanc;
  __syncthreads();
  const float m_c = bc[0];
  const double rd = 1.0 / (double)o.s1;
  const float r2 = (float)rd;
  const float c2 = (float)((-(double)m_c - (double)o.n1) * rd);
  const int B0 = (s * 16 * C_CH + c) * P4;
  int sk = 0, sk2 = 0;   // per-thread exact: sk<=5e4, sk2<=1.27e7
  #pragma unroll 1
  for (int g = 0; g < 7; ++g) {
    float4 v[7]; int idx[7];
    #pragma unroll
    for (int j = 0; j < 7; ++j) {
      const int u = t + 256 * (48 - 7 * g - j);               // REVERSE chunk order
      idx[j] = B0 + (u / P4) * PLANE_STRIDE + (u % P4);
      v[j] = x4[idx[j]];                                      // 16B/lane coalesced
    }
    #pragma unroll
    for (int j = 0; j < 7; ++j) {
      const float4 w = v[j];
      const float vv[4] = {w.x, w.y, w.z, w.w};
      uint32_t acc = 0;
      #pragma unroll
      for (int e = 0; e < 4; ++e) {
        const uint32_t k = qlevel(vv[e], r2, c2, m_c, o.s1, o.n1, o.x1);
        sk += (int)k; sk2 += (int)(k * k);
        acc |= k << (8 * e);
      }
      kq32[idx[j]] = acc;                                     // 4B/lane coalesced
    }
  }
  #pragma unroll
  for (int m = 1; m <= 32; m <<= 1) {   // wave sums: sk2 <= 8.2e8 fits int
    sk += __shfl_xor(sk, m, 64);
    sk2 += __shfl_xor(sk2, m, 64);
  }
  __shared__ uint32_t ired[8];
  const int w_ = t >> 6;
  if ((t & 63) == 0) { ired[w_] = (uint32_t)sk; ired[4 + w_] = (uint32_t)sk2; }
  __syncthreads();
  if (t == 0) {
    const int idx = c * 4 + s;
    pk[idx]  = ired[0] + ired[1] + ired[2] + ired[3];          // <=1.3e7
    pk2[idx] = ired[4] + ired[5] + ired[6] + ired[7];          // <=3.27e9, fits u32
  }
}

// ---------------- K3: S1+S2 prologue + y = lut[kq], NT store (FORWARD sweep) ----------------
__global__ __launch_bounds__(256) void k_p3(const uint32_t* __restrict__ kq32,
    const float* __restrict__ psum, const float* __restrict__ pmin,
    const float* __restrict__ pmax, const uint32_t* __restrict__ pk,
    const uint32_t* __restrict__ pk2,
    const float* __restrict__ run_mean, const float* __restrict__ run_var,
    const float* __restrict__ weight, const float* __restrict__ bias,
    natf4* __restrict__ y4) {
  __shared__ float buf4[4];
  __shared__ float bc[4];
  __shared__ float lut[256];
  const int c = blockIdx.x, s = blockIdx.y, t = threadIdx.x;
  S1Out o; s1_compute(psum, pmin, pmax, run_mean, buf4, o);
  s2_and_lut(o, pk, pk2, run_var, weight, bias, buf4, bc, lut, c);
  const int B0 = (s * 16 * C_CH + c) * P4;
  #pragma unroll 1
  for (int g = 0; g < 7; ++g) {
    uint32_t kk[7]; int idx[7];
    #pragma unroll
    for (int j = 0; j < 7; ++j) {
      const int u = t + 256 * (7 * g + j);                    // FORWARD: freshest kq first
      idx[j] = B0 + (u / P4) * PLANE_STRIDE + (u % P4);
      kk[j] = kq32[idx[j]];                                   // 4B/lane coalesced, L3-hot
    }
    #pragma unroll
    for (int j = 0; j < 7; ++j) {
      const uint32_t w = kk[j];
      natf4 out;
      out.x = lut[w & 255]; out.y = lut[(w >> 8) & 255];
      out.z = lut[(w >> 16) & 255]; out.w = lut[w >> 24];
      __builtin_nontemporal_store(out, &y4[idx[j]]);          // 16B/lane: full lines
    }
  }
}

extern "C" void kernel_launch(void* const* d_in, const int* in_sizes, int n_in,
                              void* d_out, int out_size, void* d_ws, size_t ws_size,
                              hipStream_t stream) {
  const float4* x4      = (const float4*)d_in[0];
  const float* weight   = (const float*)d_in[1];
  const float* bias     = (const float*)d_in[2];
  const float* run_mean = (const float*)d_in[3];
  const float* run_var  = (const float*)d_in[4];
  natf4* y4 = (natf4*)d_out;

  float* w = (float*)d_ws;
  float* psum = w;                       // bytes     0.. 4095
  float* pmin = w + 1024;                //        4096.. 8191
  float* pmax = w + 2048;                //        8192..12287
  uint32_t* pk  = (uint32_t*)(w + 3072); //       12288..16383
  uint32_t* pk2 = (uint32_t*)(w + 4096); //       16384..20479
  uint32_t* kq32 = (uint32_t*)((char*)d_ws + 32768);  // 51,380,224 bytes

  dim3 grid(C_CH, 4), blk(256);
  k_p1<<<grid, blk, 0, stream>>>(x4, psum, pmin, pmax);
  k_p2<<<grid, blk, 0, stream>>>(x4, kq32, psum, pmin, pmax, run_mean, pk, pk2);
  k_p3<<<grid, blk, 0, stream>>>(kq32, psum, pmin, pmax, pk, pk2,
                                 run_mean, run_var, weight, bias, y4);
}